// Round 2
// baseline (21181.487 us; speedup 1.0000x reference)
//
#include <hip/hip_runtime.h>

#define T_STEPS 2048
#define NBATCH  32
#define IN_DIM  64
#define RES     1024
#define LEAKF   0.3f
#define NCG     64   // column groups (16 cols each)
#define NBG     4    // batch groups (8 batches each)

typedef unsigned long long u64cp;

// ---------------------------------------------------------------------------
// Persistent kernel, round 2: cooperative LDS staging of the state slab.
// Grid (64,4) = 256 blocks (1 per CU), 256 threads.
// State lives in a COMPACT per-batch-group buffer sC[bg][2][1024][8] so the
// consumer-side restage is 32 KB of dense, fully-coalesced loads issued by
// all 256 threads at once (one coherence-point round trip), not 256
// dependent scalar loads per thread. Phase C then runs from LDS.
// Numerics (FMA order, reduce order) identical to the verified kernel.
// ---------------------------------------------------------------------------
__global__ __launch_bounds__(256, 1) void esn_persist(
    const float* __restrict__ inp,   // [32][2048][64]
    const float* __restrict__ Win,   // [64][1024]
    const float* __restrict__ Wres,  // [1024][1024]
    float* __restrict__ out,         // [32][2048][1024]
    float* __restrict__ sC,          // ws: [4][2][1024][8] compact state
    unsigned* __restrict__ flags)    // ws: [4][64] step flags
{
    const int tid   = threadIdx.x;
    const int c_loc = tid & 15;
    const int ks    = tid >> 4;            // 0..15 : k-chunk [64*ks, 64*ks+64)
    const int cg    = blockIdx.x;          // 0..63
    const int bg    = blockIdx.y;          // 0..3
    const int c0    = cg * 16;
    const int b0    = bg * 8;
    const int c     = c0 + c_loc;

    // Hoist this thread's Wres slice into registers: w[j] = Wres[ks*64+j][c].
    float w[64];
    {
        const float* wp = Wres + (size_t)(ks * 64) * RES + c;
        #pragma unroll
        for (int j = 0; j < 64; ++j) w[j] = wp[(size_t)j * RES];
    }

    // Staged state: row k (8 floats, 32 B) at byte addr k*32 + (k>>6)*16.
    // The +16B pad per 64-row group puts the 4 ks-groups of a wave on
    // distinct banks (offsets 0,4,8,12) -> conflict-free broadcast reads.
    __shared__ __align__(16) float sst[8256];   // 33 KB
    __shared__ float pl[16][8][17];             // k-partial reduce, 8.7 KB

    unsigned* flg = flags + bg * NCG;
    float* sCb = sC + (size_t)bg * 2 * RES * 8;

    const int fb = tid >> 4;               // finalize batch lane (tid < 128)
    float s_prev = 0.f;                    // register-carried state (b0+fb, c)

    for (int t = 0; t < T_STEPS; ++t) {
        float* sCr = sCb + ((t & 1) ^ 1) * (RES * 8);  // state t-1
        float* sCw = sCb + (t & 1) * (RES * 8);        // state t

        // ---- Phase A: input projection (state-independent; overlaps wait)
        float x = 0.f;
        if (tid < 128) {
            const float* inb = inp + ((size_t)(b0 + fb) * T_STEPS + t) * IN_DIM;
            #pragma unroll
            for (int i = 0; i < IN_DIM; i += 4) {
                const float4 v = *reinterpret_cast<const float4*>(inb + i);
                x = fmaf(v.x, Win[(size_t)(i + 0) * RES + c], x);
                x = fmaf(v.y, Win[(size_t)(i + 1) * RES + c], x);
                x = fmaf(v.z, Win[(size_t)(i + 2) * RES + c], x);
                x = fmaf(v.w, Win[(size_t)(i + 3) * RES + c], x);
            }
        }

        if (t > 0) {
            // ---- Phase B: wait for all 64 producers of step t-1.
            if (tid < NCG) {
                const unsigned tgt = (unsigned)t;
                while (__hip_atomic_load(&flg[tid], __ATOMIC_RELAXED,
                                         __HIP_MEMORY_SCOPE_AGENT) < tgt) { }
            }
            __syncthreads();

            // ---- Phase B2: cooperative stage of the 32 KB state slab.
            // Chunk m = i*256+tid covers global floats [m*4, m*4+4) and LDS
            // byte addr m*16 + (m>>7)*16 (row-group padding folded in).
            #pragma unroll
            for (int i = 0; i < 8; ++i) {
                const int m = i * 256 + tid;
                u64cp lo = __hip_atomic_load((u64cp*)(sCr + (size_t)m * 4),
                                             __ATOMIC_RELAXED, __HIP_MEMORY_SCOPE_AGENT);
                u64cp hi = __hip_atomic_load((u64cp*)(sCr + (size_t)m * 4 + 2),
                                             __ATOMIC_RELAXED, __HIP_MEMORY_SCOPE_AGENT);
                float4* dst = (float4*)((char*)sst + (size_t)m * 16 + (m >> 7) * 16);
                *dst = make_float4(__uint_as_float((unsigned)(lo       )),
                                   __uint_as_float((unsigned)(lo >> 32u)),
                                   __uint_as_float((unsigned)(hi       )),
                                   __uint_as_float((unsigned)(hi >> 32u)));
            }
            __syncthreads();
        }

        // ---- Phase C: acc(b) = sum over k-chunk of W[k][c] * s[k][b], from LDS.
        float acc0 = 0.f, acc1 = 0.f, acc2 = 0.f, acc3 = 0.f;
        float acc4 = 0.f, acc5 = 0.f, acc6 = 0.f, acc7 = 0.f;
        if (t > 0) {
            const char* base = (const char*)sst + (size_t)(ks * 64) * 32 + ks * 16;
            #pragma unroll
            for (int j = 0; j < 64; ++j) {
                const float4 sa = *reinterpret_cast<const float4*>(base + j * 32);
                const float4 sb = *reinterpret_cast<const float4*>(base + j * 32 + 16);
                const float wj = w[j];
                acc0 = fmaf(sa.x, wj, acc0);
                acc1 = fmaf(sa.y, wj, acc1);
                acc2 = fmaf(sa.z, wj, acc2);
                acc3 = fmaf(sa.w, wj, acc3);
                acc4 = fmaf(sb.x, wj, acc4);
                acc5 = fmaf(sb.y, wj, acc5);
                acc6 = fmaf(sb.z, wj, acc6);
                acc7 = fmaf(sb.w, wj, acc7);
            }
        }

        // ---- Phase D: 16-way k-reduce through LDS, then finalize.
        pl[ks][0][c_loc] = acc0;
        pl[ks][1][c_loc] = acc1;
        pl[ks][2][c_loc] = acc2;
        pl[ks][3][c_loc] = acc3;
        pl[ks][4][c_loc] = acc4;
        pl[ks][5][c_loc] = acc5;
        pl[ks][6][c_loc] = acc6;
        pl[ks][7][c_loc] = acc7;
        __syncthreads();

        if (tid < 128) {
            float sum = 0.f;
            #pragma unroll
            for (int q = 0; q < 16; ++q) sum += pl[q][fb][c_loc];

            const float nw = tanhf(x + sum);
            const float sn = fmaf(1.0f - LEAKF, s_prev, LEAKF * nw);
            s_prev = sn;

            out[((size_t)(b0 + fb) * T_STEPS + t) * RES + c] = sn;
            __hip_atomic_store(sCw + (size_t)c * 8 + fb, sn,
                               __ATOMIC_RELAXED, __HIP_MEMORY_SCOPE_AGENT);
        }
        __syncthreads();   // all waves drain stores before the publish

        // ---- Phase E: publish completion of step t.
        if (tid == 0)
            __hip_atomic_store(&flg[cg], (unsigned)(t + 1),
                               __ATOMIC_RELAXED, __HIP_MEMORY_SCOPE_AGENT);
    }
}

// ---------------------------------------------------------------------------
// Fallback: proven per-step kernel (used only if ws too small).
// ---------------------------------------------------------------------------
__global__ __launch_bounds__(256) void esn_step(
    const float* __restrict__ inp,
    const float* __restrict__ Win,
    const float* __restrict__ Wres,
    float* __restrict__ out,
    float* __restrict__ sT,
    int t)
{
    const int tid   = threadIdx.x;
    const int c_loc = tid & 15;
    const int ks    = tid >> 4;
    const int c0    = blockIdx.x * 16;
    const int b0    = blockIdx.y * 8;
    const int c     = c0 + c_loc;

    const float* sTr = sT + ((t & 1) ^ 1) * (RES * NBATCH);
    float*       sTw = sT + (t & 1) * (RES * NBATCH);

    float acc0 = 0.f, acc1 = 0.f, acc2 = 0.f, acc3 = 0.f;
    float acc4 = 0.f, acc5 = 0.f, acc6 = 0.f, acc7 = 0.f;

    if (t > 0) {
        const int kbeg = ks * 64;
        const float* wp = Wres + (size_t)kbeg * RES + c;
        const float* sp = sTr + kbeg * NBATCH + b0;
        #pragma unroll 4
        for (int j = 0; j < 64; ++j) {
            const float w = wp[(size_t)j * RES];
            const float4 sa = *reinterpret_cast<const float4*>(sp + j * NBATCH);
            const float4 sb = *reinterpret_cast<const float4*>(sp + j * NBATCH + 4);
            acc0 = fmaf(sa.x, w, acc0);
            acc1 = fmaf(sa.y, w, acc1);
            acc2 = fmaf(sa.z, w, acc2);
            acc3 = fmaf(sa.w, w, acc3);
            acc4 = fmaf(sb.x, w, acc4);
            acc5 = fmaf(sb.y, w, acc5);
            acc6 = fmaf(sb.z, w, acc6);
            acc7 = fmaf(sb.w, w, acc7);
        }
    }

    __shared__ float pl[16][8][17];
    pl[ks][0][c_loc] = acc0;
    pl[ks][1][c_loc] = acc1;
    pl[ks][2][c_loc] = acc2;
    pl[ks][3][c_loc] = acc3;
    pl[ks][4][c_loc] = acc4;
    pl[ks][5][c_loc] = acc5;
    pl[ks][6][c_loc] = acc6;
    pl[ks][7][c_loc] = acc7;
    __syncthreads();

    if (tid < 128) {
        const int b  = tid >> 4;
        const int cl = tid & 15;
        const int cgl = c0 + cl;
        const int bgl = b0 + b;

        float sum = 0.f;
        #pragma unroll
        for (int q = 0; q < 16; ++q) sum += pl[q][b][cl];

        const float* inb = inp + ((size_t)bgl * T_STEPS + t) * IN_DIM;
        float x = 0.f;
        #pragma unroll 8
        for (int i = 0; i < IN_DIM; ++i)
            x = fmaf(inb[i], Win[(size_t)i * RES + cgl], x);

        const float a  = x + sum;
        const float nw = tanhf(a);
        const float spv = (t > 0) ? sTr[cgl * NBATCH + bgl] : 0.f;
        const float sn = fmaf(1.0f - LEAKF, spv, LEAKF * nw);

        out[((size_t)bgl * T_STEPS + t) * RES + cgl] = sn;
        sTw[cgl * NBATCH + bgl] = sn;
    }
}

extern "C" void kernel_launch(void* const* d_in, const int* in_sizes, int n_in,
                              void* d_out, int out_size, void* d_ws, size_t ws_size,
                              hipStream_t stream)
{
    const float* inp  = (const float*)d_in[0];   // [32,2048,64]
    const float* Win  = (const float*)d_in[1];   // [64,1024]
    const float* Wres = (const float*)d_in[2];   // [1024,1024]
    float* out = (float*)d_out;                  // [32,2048,1024]

    const size_t stateBytes = (size_t)NBG * 2 * RES * 8 * sizeof(float);  // 256 KB
    const size_t flagBytes  = (size_t)NBG * NCG * sizeof(unsigned);       // 1 KB

    if (ws_size >= stateBytes + flagBytes) {
        float* sC = (float*)d_ws;
        unsigned* flags = (unsigned*)((char*)d_ws + stateBytes);
        hipMemsetAsync(flags, 0, flagBytes, stream);   // re-zeroed every replay
        hipLaunchKernelGGL(esn_persist, dim3(NCG, NBG), dim3(256), 0, stream,
                           inp, Win, Wres, out, sC, flags);
        return;
    }

    // Workspace too small: proven per-step path.
    float* sT = (float*)d_ws;   // [2][1024][32]
    dim3 grid(64, 4), blk(256);
    for (int t = 0; t < T_STEPS; ++t) {
        hipLaunchKernelGGL(esn_step, grid, blk, 0, stream,
                           inp, Win, Wres, out, sT, t);
    }
}